// Round 11
// baseline (232.259 us; speedup 1.0000x reference)
//
#include <hip/hip_runtime.h>
#include <math.h>

#define N_NODES 100000
#define N_EDGES 800000
#define F 128
#define NBUCK ((N_NODES + 255) / 256)   // 391 buckets of 256 target nodes
#define CPAD 32                         // counter stride in ints = 128B = own L2 line
#define SCAP 3072                       // per-bucket stage capacity (mean 2048, +22 sigma)
#define BSPAN 4096                      // padded CSR span per bucket (mean 2944, +25 sigma)
#define EPB 2048                        // edges per k_fill3 block
#define FILL_BLOCKS ((N_EDGES + EPB - 1) / EPB)   // 391

typedef __attribute__((ext_vector_type(8))) short short8;
typedef __attribute__((ext_vector_type(4))) float floatx4;

__device__ __forceinline__ unsigned short f2bf(float f) {
    unsigned u = __float_as_uint(f);
    u += 0x7fffu + ((u >> 16) & 1u);          // round-to-nearest-even
    return (unsigned short)(u >> 16);
}
__device__ __forceinline__ float bf_lo(unsigned u) { return __uint_as_float(u << 16); }
__device__ __forceinline__ float bf_hi(unsigned u) { return __uint_as_float(u & 0xffff0000u); }
__device__ __forceinline__ unsigned pack2(float a, float b) {
    return (unsigned)f2bf(a) | ((unsigned)f2bf(b) << 16);
}

// ---------------- CSR build: block-aggregated bucketed counting sort ----------------
// Round-9 lesson: with padded+replicated counters, per-line serialization is
// ~2us, yet k_fill2 took 42us at VALUBusy 0.8% -> the cost is the COUNT of
// fully-divergent small ops. k_fill3 amortizes: each block LDS-counting-sorts
// 2048 edges by bucket, then ONE global atomicAdd per (block,bucket) and
// coalesced run-flushes. (r10: confirmed, dropped out of top-5.)

__global__ __launch_bounds__(256) void k_fill3(const int* __restrict__ row,
                                               const int* __restrict__ col,
                                               int* __restrict__ bcnt,
                                               unsigned* __restrict__ stage) {
    __shared__ int hist[512];                  // histogram, then reused as cursor
    __shared__ int base[512];                  // exclusive prefix (block-local)
    __shared__ int gpos[NBUCK];                // global base per bucket
    __shared__ int sA[256], sB[256];
    __shared__ unsigned buf[EPB];              // block-locally sorted entries
    __shared__ unsigned short bkt[EPB];        // bucket of each sorted slot
    int t = threadIdx.x, blk = blockIdx.x;
    int e0 = blk * EPB;
    int nedge = N_EDGES - e0; if (nedge > EPB) nedge = EPB;

    hist[t] = 0; hist[256 + t] = 0;
    __syncthreads();

    int myb[8]; unsigned myv[8];
#pragma unroll
    for (int k = 0; k < 8; ++k) {
        int i = t + k * 256;                   // coalesced within wave
        myb[k] = -1;
        if (i < nedge) {
            int e = e0 + i;
            int r = row[e], c = col[e];
            int bk = c >> 8;
            myb[k] = bk;
            myv[k] = ((unsigned)(c & 255) << 20) | (unsigned)(r + 1);
            atomicAdd(&hist[bk], 1);
        }
    }
    __syncthreads();

    // exclusive scan over 512 (two sequential 256-wide Hillis-Steele scans)
    int v0 = hist[t], v1 = hist[256 + t];
    sA[t] = v0; __syncthreads();
#pragma unroll
    for (int off = 1; off < 256; off <<= 1) {
        int u = (t >= off) ? sA[t - off] : 0;
        __syncthreads(); sA[t] += u; __syncthreads();
    }
    int tot0 = sA[255];
    sB[t] = v1; __syncthreads();
#pragma unroll
    for (int off = 1; off < 256; off <<= 1) {
        int u = (t >= off) ? sB[t - off] : 0;
        __syncthreads(); sB[t] += u; __syncthreads();
    }
    base[t] = sA[t] - v0;
    base[256 + t] = tot0 + sB[t] - v1;
    __syncthreads();
    hist[t] = base[t]; hist[256 + t] = base[256 + t];   // cursor = base
    __syncthreads();

    // scatter into block-local sorted order
#pragma unroll
    for (int k = 0; k < 8; ++k) {
        if (myb[k] >= 0) {
            int pos = atomicAdd(&hist[myb[k]], 1);
            buf[pos] = myv[k];
            bkt[pos] = (unsigned short)myb[k];
        }
    }
    __syncthreads();

    // one global atomic per touched bucket (counters on own 128B lines)
    for (int i = t; i < NBUCK; i += 256) {
        int cnt = hist[i] - base[i];
        gpos[i] = cnt > 0 ? atomicAdd(&bcnt[i * CPAD], cnt) : 0;
    }
    __syncthreads();

    // flush runs: consecutive i in a run -> consecutive global addresses
    for (int i = t; i < nedge; i += 256) {
        int bk = bkt[i];
        int op = gpos[bk] + (i - base[bk]);
        if (op < SCAP)                          // +22 sigma; guards OOB
            stage[(size_t)bk * SCAP + op] = buf[i];
    }
}

// Pass 2: one block per bucket. Drain the single stage segment: LDS histogram ->
// LDS scan of 8-padded counts -> LDS scatter -> coalesced flush. Emits rp2, dinv, dinv2.

__global__ __launch_bounds__(256) void k_build(const int* __restrict__ bcnt,
                                               const unsigned* __restrict__ stage,
                                               unsigned* __restrict__ csr,
                                               int2* __restrict__ rp2,
                                               float* __restrict__ dinv,
                                               float* __restrict__ dinv2) {
    __shared__ int hist[256];
    __shared__ int sc[256];
    __shared__ int cursor[256];
    __shared__ int spanTot;
    __shared__ unsigned img[BSPAN];                // 16 KB bucket-local CSR image
    int bk = blockIdx.x, t = threadIdx.x;
    int n = bcnt[bk * CPAD]; n = n < SCAP ? n : SCAP;
    const unsigned* sp = stage + (size_t)bk * SCAP;
    hist[t] = 0;
    __syncthreads();
    for (int i = t; i < n; i += 256) atomicAdd(&hist[sp[i] >> 20], 1);
    __syncthreads();
    int cdeg = hist[t];
    int pad = (cdeg + 7) & ~7;                     // rows 8-padded (hop loads uint4 pairs)
    sc[t] = pad;
    __syncthreads();
#pragma unroll
    for (int off = 1; off < 256; off <<= 1) {      // Hillis-Steele inclusive scan
        int u = (t >= off) ? sc[t - off] : 0;
        __syncthreads();
        sc[t] += u;
        __syncthreads();
    }
    int excl = sc[t] - pad;
    if (t == 255) spanTot = sc[255];
    cursor[t] = excl;
    __syncthreads();
    int tot = spanTot;
    int node = bk * 256 + t;
    if (node < N_NODES) {
        int base = bk * BSPAN;
        rp2[node] = (int2){base + excl, base + excl + pad};
        float d = rsqrtf((float)cdeg + 1.0f);      // +1 self-loop
        dinv[node] = d; dinv2[node] = d * d;
    }
    for (int i = t; i < tot; i += 256) img[i] = 0u;   // pad slots -> zero row
    __syncthreads();
    for (int i = t; i < n; i += 256) {
        unsigned v = sp[i];
        int pos = atomicAdd(&cursor[v >> 20], 1);
        img[pos] = v & 0xFFFFFu;                   // r+1 (rows shifted +1)
    }
    __syncthreads();
    unsigned* op = csr + (size_t)bk * BSPAN;
    for (int i = t; i < tot; i += 256) op[i] = img[i];   // coalesced flush
}

// prep: xb[(v+1)] = bf16(dinv[v] * x[v])  (shifted rows; row 0 = zeros).
// Also zeroes row 0 of h1b, and converts W -> bf16 (32 KB) for the GEMM's
// direct fragment loads. Runs after k_build (needs dinv).
__global__ void k_prep(const float4* __restrict__ x, const float* __restrict__ dinv,
                       const float4* __restrict__ W4, uint2* __restrict__ wbf,
                       uint2* __restrict__ xb, uint2* __restrict__ h1b) {
    int i = blockIdx.x * blockDim.x + threadIdx.x;
    if (i < 32) { xb[i] = (uint2){0u, 0u}; h1b[i] = (uint2){0u, 0u}; }
    if (i < 4096) {                            // 4096 float4 = all of W (64 KB)
        float4 wv = W4[i];
        uint2 o; o.x = pack2(wv.x, wv.y); o.y = pack2(wv.z, wv.w);
        wbf[i] = o;                            // row-major bf16 W, 256 B/row
    }
    if (i >= N_NODES * 32) return;
    int node = i >> 5;
    float d = dinv[node];
    float4 v = x[i];
    uint2 o; o.x = pack2(d * v.x, d * v.y); o.y = pack2(d * v.z, d * v.w);
    xb[i + 32] = o;                            // row node+1
}

// ---------------- propagation: 4 nodes/wave, 16B/lane gathers ----------------
// acc = y[c] + sum y[r]; out = scale[c] * acc  (scale = dinv^2 for hop1 -> y1,
// dinv for hop2 -> h2). Rows shifted +1; pad entries hit zero row 0 (cache-hot).
// Round-10 restructure: 16 lanes x uint4 cover a 256B row (was 32 x uint2),
// so each gather instruction moves 1KB serving 4 nodes -> 0.31 VMEM/edge
// (was 0.625). Same bytes, same per-row coalescing; targets the gather
// issue/latency bound. Cost: max-of-4 degree tail (~+25% masked iters).

__global__ __launch_bounds__(256) void k_hop(const int2* __restrict__ rp2,
                                             const unsigned* __restrict__ csr,
                                             const float* __restrict__ scale,
                                             const uint4* __restrict__ src,
                                             uint4* __restrict__ dst) {
    int wv = (blockIdx.x * blockDim.x + threadIdx.x) >> 6;
    int lane = threadIdx.x & 63;
    int q = lane >> 4, off = lane & 15;             // quarter-wave, 16B unit in row
    int node = wv * 4 + q;                          // 25k waves exact (100k/4)
    if (node >= N_NODES) return;
    uint4 u = src[(size_t)(node + 1) * 16 + off];   // own (pre-scaled) row
    float a0 = bf_lo(u.x), a1 = bf_hi(u.x);
    float a2 = bf_lo(u.y), a3 = bf_hi(u.y);
    float a4 = bf_lo(u.z), a5 = bf_hi(u.z);
    float a6 = bf_lo(u.w), a7 = bf_hi(u.w);
    int2 rp = rp2[node];
    int e = rp.x, end = rp.y;                       // end-e is a multiple of 8
    for (; e < end; e += 8) {
        const uint4* cp = (const uint4*)(csr + e);  // 16B-aligned (8-padded rows)
        uint4 c0 = cp[0], c1 = cp[1];               // 8 indices per quarter
        unsigned idx[8] = {c0.x, c0.y, c0.z, c0.w, c1.x, c1.y, c1.z, c1.w};
#pragma unroll
        for (int j = 0; j < 8; ++j) {
            uint4 v = src[(size_t)idx[j] * 16 + off];
            a0 += bf_lo(v.x); a1 += bf_hi(v.x);
            a2 += bf_lo(v.y); a3 += bf_hi(v.y);
            a4 += bf_lo(v.z); a5 += bf_hi(v.z);
            a6 += bf_lo(v.w); a7 += bf_hi(v.w);
        }
    }
    float s = scale[node];
    uint4 o;
    o.x = pack2(s * a0, s * a1); o.y = pack2(s * a2, s * a3);
    o.z = pack2(s * a4, s * a5); o.w = pack2(s * a6, s * a7);
    dst[(size_t)(node + 1) * 16 + off] = o;
}

// ---------------- MFMA GEMM + bias + log_softmax ----------------
// Rounds 4-8 empirical law: this kernel's HBM-visible traffic scales with GRID
// SIZE, not store shape (512: 63 MB ideal / 1024: 242 MB / 1563: 306 MB;
// identical at scattered, nontemporal, and LDS-staged full-line stores). The
// concurrency-driven traffic penalty exceeds any latency-hiding gain, so the
// minimum-traffic point grid=512 (2 blocks/CU) is the operating point. DO NOT
// raise the grid or occupancy here without re-measuring FETCH/WRITE.

__global__ __launch_bounds__(256) void k_gemm_lsm_mfma(const unsigned short* __restrict__ h,
                                                       const unsigned short* __restrict__ wbf,
                                                       const float* __restrict__ b,
                                                       float* __restrict__ out) {
    int tid = threadIdx.x;
    int lane = tid & 63;
    int wave = tid >> 6;
    int m = lane & 15, quad = lane >> 4;

    float bv[8];
#pragma unroll
    for (int t = 0; t < 8; ++t) bv[t] = b[16 * t + m];

    const int ngroups = (N_NODES + 63) / 64;        // 1563 groups of 64 nodes
    for (int g = blockIdx.x; g < ngroups; g += gridDim.x) {
        int gbase = g * 64 + wave * 16;
        int nodeA = gbase + m;
        int node_c = nodeA < N_NODES ? nodeA : N_NODES - 1;
        short8 a[4];
#pragma unroll
        for (int ks = 0; ks < 4; ++ks)
            a[ks] = *(const short8*)(h + (size_t)node_c * 128 + ks * 32 + quad * 8);
        floatx4 acc[8];
#pragma unroll
        for (int t = 0; t < 8; ++t) acc[t] = (floatx4){bv[t], bv[t], bv[t], bv[t]};
        // B fragment (t,ks): lane holds W[16t+m][ks*32+quad*8 .. +8) as bf16,
        // read from the 32 KB wbf image (L1/L2-hot across groups).
#pragma unroll
        for (int t = 0; t < 8; ++t) {
#pragma unroll
            for (int ks = 0; ks < 4; ++ks) {
                short8 bf = *(const short8*)(wbf + (size_t)(16 * t + m) * 128 + ks * 32 + quad * 8);
                acc[t] = __builtin_amdgcn_mfma_f32_16x16x32_bf16(a[ks], bf, acc[t], 0, 0, 0);
            }
        }

        // D layout: row = gbase + quad*4 + r, col = 16t + m
#pragma unroll
        for (int r = 0; r < 4; ++r) {
            float mx = acc[0][r];
#pragma unroll
            for (int t = 1; t < 8; ++t) mx = fmaxf(mx, acc[t][r]);
#pragma unroll
            for (int msk = 1; msk < 16; msk <<= 1) mx = fmaxf(mx, __shfl_xor(mx, msk));
            float sm = 0.f;
#pragma unroll
            for (int t = 0; t < 8; ++t) sm += __expf(acc[t][r] - mx);
#pragma unroll
            for (int msk = 1; msk < 16; msk <<= 1) sm += __shfl_xor(sm, msk);
            float l = mx + __logf(sm);
            int rown = gbase + quad * 4 + r;
            if (rown < N_NODES) {
                float* op = out + (size_t)rown * 128 + m;
#pragma unroll
                for (int t = 0; t < 8; ++t) op[16 * t] = acc[t][r] - l;
            }
        }
    }
}

// ---------------- launch ----------------

extern "C" void kernel_launch(void* const* d_in, const int* in_sizes, int n_in,
                              void* d_out, int out_size, void* d_ws, size_t ws_size,
                              hipStream_t stream) {
    const float* x = (const float*)d_in[0];
    const float* W = (const float*)d_in[1];
    const float* b = (const float*)d_in[2];
    const int* edge = (const int*)d_in[3];
    const int* row = edge;             // source nodes j
    const int* col = edge + N_EDGES;   // target nodes i
    float* out = (float*)d_out;

    // workspace layout (4B word offsets)
    int*      bcnt  = (int*)d_ws;                     // NBUCK padded ctrs (50KB) - only memset
    float*    dinv  = (float*)(bcnt + NBUCK * CPAD + 256);
    float*    dinv2 = dinv + 102400;                  // 100k
    int2*     rp2   = (int2*)(dinv2 + 102400);        // 100k (start,end)
    unsigned* csr   = (unsigned*)(rp2 + 102400);      // NBUCK*BSPAN = 1.6M (6.4 MB)
    uint2*    xb    = (uint2*)(csr + (size_t)NBUCK * BSPAN);  // (N+1)*32 uint2 = 25.6 MB
    uint2*    h1b   = xb + 32 * (N_NODES + 1);        // (N+1)*32 uint2
    uint2*    h2b   = xb;                             // reuse: xb dead after hop 1
    // stage aliases h1b past its zero-row (h1b is only written by k_hop #1,
    // which launches after k_build has consumed stage; stream order serializes).
    unsigned* stage = (unsigned*)(h1b + 32);          // NBUCK*SCAP*4 = 4.8 MB
    uint2*    wbf   = h1b + 32 * (N_NODES + 1);       // 4096 uint2 = 32 KB bf16 W

    int nb_prep = (N_NODES * 32 + 255) / 256;         // 12500

    (void)hipMemsetAsync(bcnt, 0, (size_t)NBUCK * CPAD * 4, stream);   // 50 KB
    k_fill3<<<FILL_BLOCKS, 256, 0, stream>>>(row, col, bcnt, stage);
    k_build<<<NBUCK, 256, 0, stream>>>(bcnt, stage, csr, rp2, dinv, dinv2);
    k_prep<<<nb_prep, 256, 0, stream>>>((const float4*)x, dinv, (const float4*)W, wbf, xb, h1b);

    int hop_blocks = (N_NODES / 4 * 64) / 256;        // 6250: one wave per 4 nodes
    k_hop<<<hop_blocks, 256, 0, stream>>>(rp2, csr, dinv2, (const uint4*)xb, (uint4*)h1b);  // -> y1
    k_hop<<<hop_blocks, 256, 0, stream>>>(rp2, csr, dinv, (const uint4*)h1b, (uint4*)h2b);  // -> h2

    k_gemm_lsm_mfma<<<512, 256, 0, stream>>>((const unsigned short*)(h2b + 32),
                                             (const unsigned short*)wbf, b, out);
}

// Round 12
// 219.334 us; speedup vs baseline: 1.0589x; 1.0589x over previous
//
#include <hip/hip_runtime.h>
#include <math.h>

#define N_NODES 100000
#define N_EDGES 800000
#define F 128
#define NBUCK ((N_NODES + 255) / 256)   // 391 buckets of 256 target nodes
#define CPAD 32                         // counter stride in ints = 128B = own L2 line
#define SCAP 3072                       // per-bucket stage capacity (mean 2048, +22 sigma)
#define BSPAN 4096                      // padded CSR span per bucket (mean 2944, +25 sigma)
#define EPB 2048                        // edges per k_fill3 block
#define FILL_BLOCKS ((N_EDGES + EPB - 1) / EPB)   // 391

typedef __attribute__((ext_vector_type(8))) short short8;
typedef __attribute__((ext_vector_type(4))) float floatx4;

__device__ __forceinline__ unsigned short f2bf(float f) {
    unsigned u = __float_as_uint(f);
    u += 0x7fffu + ((u >> 16) & 1u);          // round-to-nearest-even
    return (unsigned short)(u >> 16);
}
__device__ __forceinline__ float bf_lo(unsigned u) { return __uint_as_float(u << 16); }
__device__ __forceinline__ float bf_hi(unsigned u) { return __uint_as_float(u & 0xffff0000u); }
__device__ __forceinline__ unsigned pack2(float a, float b) {
    return (unsigned)f2bf(a) | ((unsigned)f2bf(b) << 16);
}

// ---------------- CSR build: block-aggregated bucketed counting sort ----------------
// Round-9 lesson: with padded+replicated counters, per-line serialization is
// ~2us, yet k_fill2 took 42us at VALUBusy 0.8% -> the cost is the COUNT of
// fully-divergent small ops. k_fill3 amortizes: each block LDS-counting-sorts
// 2048 edges by bucket, then ONE global atomicAdd per (block,bucket) and
// coalesced run-flushes. (r10: confirmed, dropped out of top-5.)

__global__ __launch_bounds__(256) void k_fill3(const int* __restrict__ row,
                                               const int* __restrict__ col,
                                               int* __restrict__ bcnt,
                                               unsigned* __restrict__ stage) {
    __shared__ int hist[512];                  // histogram, then reused as cursor
    __shared__ int base[512];                  // exclusive prefix (block-local)
    __shared__ int gpos[NBUCK];                // global base per bucket
    __shared__ int sA[256], sB[256];
    __shared__ unsigned buf[EPB];              // block-locally sorted entries
    __shared__ unsigned short bkt[EPB];        // bucket of each sorted slot
    int t = threadIdx.x, blk = blockIdx.x;
    int e0 = blk * EPB;
    int nedge = N_EDGES - e0; if (nedge > EPB) nedge = EPB;

    hist[t] = 0; hist[256 + t] = 0;
    __syncthreads();

    int myb[8]; unsigned myv[8];
#pragma unroll
    for (int k = 0; k < 8; ++k) {
        int i = t + k * 256;                   // coalesced within wave
        myb[k] = -1;
        if (i < nedge) {
            int e = e0 + i;
            int r = row[e], c = col[e];
            int bk = c >> 8;
            myb[k] = bk;
            myv[k] = ((unsigned)(c & 255) << 20) | (unsigned)(r + 1);
            atomicAdd(&hist[bk], 1);
        }
    }
    __syncthreads();

    // exclusive scan over 512 (two sequential 256-wide Hillis-Steele scans)
    int v0 = hist[t], v1 = hist[256 + t];
    sA[t] = v0; __syncthreads();
#pragma unroll
    for (int off = 1; off < 256; off <<= 1) {
        int u = (t >= off) ? sA[t - off] : 0;
        __syncthreads(); sA[t] += u; __syncthreads();
    }
    int tot0 = sA[255];
    sB[t] = v1; __syncthreads();
#pragma unroll
    for (int off = 1; off < 256; off <<= 1) {
        int u = (t >= off) ? sB[t - off] : 0;
        __syncthreads(); sB[t] += u; __syncthreads();
    }
    base[t] = sA[t] - v0;
    base[256 + t] = tot0 + sB[t] - v1;
    __syncthreads();
    hist[t] = base[t]; hist[256 + t] = base[256 + t];   // cursor = base
    __syncthreads();

    // scatter into block-local sorted order
#pragma unroll
    for (int k = 0; k < 8; ++k) {
        if (myb[k] >= 0) {
            int pos = atomicAdd(&hist[myb[k]], 1);
            buf[pos] = myv[k];
            bkt[pos] = (unsigned short)myb[k];
        }
    }
    __syncthreads();

    // one global atomic per touched bucket (counters on own 128B lines)
    for (int i = t; i < NBUCK; i += 256) {
        int cnt = hist[i] - base[i];
        gpos[i] = cnt > 0 ? atomicAdd(&bcnt[i * CPAD], cnt) : 0;
    }
    __syncthreads();

    // flush runs: consecutive i in a run -> consecutive global addresses
    for (int i = t; i < nedge; i += 256) {
        int bk = bkt[i];
        int op = gpos[bk] + (i - base[bk]);
        if (op < SCAP)                          // +22 sigma; guards OOB
            stage[(size_t)bk * SCAP + op] = buf[i];
    }
}

// Pass 2: one block per bucket. Drain the single stage segment: LDS histogram ->
// LDS scan of 8-padded counts -> LDS scatter -> coalesced flush. Emits rp2, dinv, dinv2.

__global__ __launch_bounds__(256) void k_build(const int* __restrict__ bcnt,
                                               const unsigned* __restrict__ stage,
                                               unsigned* __restrict__ csr,
                                               int2* __restrict__ rp2,
                                               float* __restrict__ dinv,
                                               float* __restrict__ dinv2) {
    __shared__ int hist[256];
    __shared__ int sc[256];
    __shared__ int cursor[256];
    __shared__ int spanTot;
    __shared__ unsigned img[BSPAN];                // 16 KB bucket-local CSR image
    int bk = blockIdx.x, t = threadIdx.x;
    int n = bcnt[bk * CPAD]; n = n < SCAP ? n : SCAP;
    const unsigned* sp = stage + (size_t)bk * SCAP;
    hist[t] = 0;
    __syncthreads();
    for (int i = t; i < n; i += 256) atomicAdd(&hist[sp[i] >> 20], 1);
    __syncthreads();
    int cdeg = hist[t];
    int pad = (cdeg + 7) & ~7;                     // rows 8-padded (hop loads uint4 pairs)
    sc[t] = pad;
    __syncthreads();
#pragma unroll
    for (int off = 1; off < 256; off <<= 1) {      // Hillis-Steele inclusive scan
        int u = (t >= off) ? sc[t - off] : 0;
        __syncthreads();
        sc[t] += u;
        __syncthreads();
    }
    int excl = sc[t] - pad;
    if (t == 255) spanTot = sc[255];
    cursor[t] = excl;
    __syncthreads();
    int tot = spanTot;
    int node = bk * 256 + t;
    if (node < N_NODES) {
        int base = bk * BSPAN;
        rp2[node] = (int2){base + excl, base + excl + pad};
        float d = rsqrtf((float)cdeg + 1.0f);      // +1 self-loop
        dinv[node] = d; dinv2[node] = d * d;
    }
    for (int i = t; i < tot; i += 256) img[i] = 0u;   // pad slots -> zero row
    __syncthreads();
    for (int i = t; i < n; i += 256) {
        unsigned v = sp[i];
        int pos = atomicAdd(&cursor[v >> 20], 1);
        img[pos] = v & 0xFFFFFu;                   // r+1 (rows shifted +1)
    }
    __syncthreads();
    unsigned* op = csr + (size_t)bk * BSPAN;
    for (int i = t; i < tot; i += 256) op[i] = img[i];   // coalesced flush
}

// prep: xb[(v+1)] = bf16(dinv[v] * x[v])  (shifted rows; row 0 = zeros).
// Also zeroes row 0 of h1b, and converts W -> bf16 (32 KB) for the GEMM's
// direct fragment loads. Runs after k_build (needs dinv).
__global__ void k_prep(const float4* __restrict__ x, const float* __restrict__ dinv,
                       const float4* __restrict__ W4, uint2* __restrict__ wbf,
                       uint2* __restrict__ xb, uint2* __restrict__ h1b) {
    int i = blockIdx.x * blockDim.x + threadIdx.x;
    if (i < 32) { xb[i] = (uint2){0u, 0u}; h1b[i] = (uint2){0u, 0u}; }
    if (i < 4096) {                            // 4096 float4 = all of W (64 KB)
        float4 wv = W4[i];
        uint2 o; o.x = pack2(wv.x, wv.y); o.y = pack2(wv.z, wv.w);
        wbf[i] = o;                            // row-major bf16 W, 256 B/row
    }
    if (i >= N_NODES * 32) return;
    int node = i >> 5;
    float d = dinv[node];
    float4 v = x[i];
    uint2 o; o.x = pack2(d * v.x, d * v.y); o.y = pack2(d * v.z, d * v.w);
    xb[i + 32] = o;                            // row node+1
}

// ---------------- propagation: weight-free gather, 2 nodes/wave, exact 8-deep ----------------
// acc = y[c] + sum y[r]; out = scale[c] * acc  (scale = dinv^2 for hop1 -> y1,
// dinv for hop2 -> h2). Rows shifted +1; pad entries hit zero row 0 (cache-hot).
// Round-11 lesson: 4-node/uint4 variant REGRESSED (44.2us vs ~38; divergence
// tail grew, issue rate was not the bound). This 2-node/uint2 shape moves
// ~263 MB logical per hop in ~38us ~= 6+ TB/s -- at the memory-system
// ceiling for this pattern. DO NOT restructure without traffic reduction.

__global__ __launch_bounds__(256) void k_hop(const int2* __restrict__ rp2,
                                             const unsigned* __restrict__ csr,
                                             const float* __restrict__ scale,
                                             const uint2* __restrict__ src,
                                             uint2* __restrict__ dst) {
    int wv = (blockIdx.x * blockDim.x + threadIdx.x) >> 6;
    int lane = threadIdx.x & 63;
    int half = lane >> 5, off = lane & 31;
    int node = wv * 2 + half;                       // 50k waves exact
    if (node >= N_NODES) return;
    uint2 u = src[(size_t)(node + 1) * 32 + off];   // own (pre-scaled) row
    float a0 = bf_lo(u.x), a1 = bf_hi(u.x);
    float a2 = bf_lo(u.y), a3 = bf_hi(u.y);
    int2 rp = rp2[node];
    int e = rp.x, end = rp.y;                       // end-e is a multiple of 8
    for (; e < end; e += 8) {
        const uint4* cp = (const uint4*)(csr + e);  // 16B-aligned (8-padded rows)
        uint4 c0 = cp[0], c1 = cp[1];               // 8 indices, broadcast loads
        unsigned idx[8] = {c0.x, c0.y, c0.z, c0.w, c1.x, c1.y, c1.z, c1.w};
#pragma unroll
        for (int j = 0; j < 8; ++j) {
            uint2 v = src[(size_t)idx[j] * 32 + off];
            a0 += bf_lo(v.x); a1 += bf_hi(v.x);
            a2 += bf_lo(v.y); a3 += bf_hi(v.y);
        }
    }
    float s = scale[node];
    uint2 o; o.x = pack2(s * a0, s * a1); o.y = pack2(s * a2, s * a3);
    dst[(size_t)(node + 1) * 32 + off] = o;
}

// ---------------- MFMA GEMM + bias + log_softmax ----------------
// Rounds 4-8 empirical law: this kernel's HBM-visible traffic scales with GRID
// SIZE, not store shape (512: 63 MB ideal / 1024: 242 MB / 1563: 306 MB).
// grid=512 (2 blocks/CU) is the minimum-traffic operating point. DO NOT raise
// grid/occupancy without re-measuring FETCH/WRITE.
// Round-12: software-pipeline the per-group A load -- prefetch the NEXT
// group's 4 short8 fragments (branchless clamped address) before the current
// group's MFMA+epilogue, hiding the ~900-cycle L3/HBM latency that was
// dependency-serialized with the epilogue. Same grid, same access pattern.

__global__ __launch_bounds__(256) void k_gemm_lsm_mfma(const unsigned short* __restrict__ h,
                                                       const unsigned short* __restrict__ wbf,
                                                       const float* __restrict__ b,
                                                       float* __restrict__ out) {
    int tid = threadIdx.x;
    int lane = tid & 63;
    int wave = tid >> 6;
    int m = lane & 15, quad = lane >> 4;

    float bv[8];
#pragma unroll
    for (int t = 0; t < 8; ++t) bv[t] = b[16 * t + m];

    const int ngroups = (N_NODES + 63) / 64;        // 1563 groups of 64 nodes
    int g0 = blockIdx.x;
    short8 a[4];
    if (g0 < ngroups) {                             // preload first group's A
        int nodeA = g0 * 64 + wave * 16 + m;
        int node_c = nodeA < N_NODES ? nodeA : N_NODES - 1;
#pragma unroll
        for (int ks = 0; ks < 4; ++ks)
            a[ks] = *(const short8*)(h + (size_t)node_c * 128 + ks * 32 + quad * 8);
    }
    for (int g = g0; g < ngroups; g += gridDim.x) {
        // prefetch next group's A (clamped; extra load on last iter is cached)
        int gn = g + gridDim.x; if (gn >= ngroups) gn = g;
        int nodeN = gn * 64 + wave * 16 + m;
        int node_n = nodeN < N_NODES ? nodeN : N_NODES - 1;
        short8 an[4];
#pragma unroll
        for (int ks = 0; ks < 4; ++ks)
            an[ks] = *(const short8*)(h + (size_t)node_n * 128 + ks * 32 + quad * 8);

        int gbase = g * 64 + wave * 16;
        floatx4 acc[8];
#pragma unroll
        for (int t = 0; t < 8; ++t) acc[t] = (floatx4){bv[t], bv[t], bv[t], bv[t]};
        // B fragment (t,ks): lane holds W[16t+m][ks*32+quad*8 .. +8) as bf16,
        // read from the 32 KB wbf image (L1/L2-hot across groups).
#pragma unroll
        for (int t = 0; t < 8; ++t) {
#pragma unroll
            for (int ks = 0; ks < 4; ++ks) {
                short8 bf = *(const short8*)(wbf + (size_t)(16 * t + m) * 128 + ks * 32 + quad * 8);
                acc[t] = __builtin_amdgcn_mfma_f32_16x16x32_bf16(a[ks], bf, acc[t], 0, 0, 0);
            }
        }

        // D layout: row = gbase + quad*4 + r, col = 16t + m
#pragma unroll
        for (int r = 0; r < 4; ++r) {
            float mx = acc[0][r];
#pragma unroll
            for (int t = 1; t < 8; ++t) mx = fmaxf(mx, acc[t][r]);
#pragma unroll
            for (int msk = 1; msk < 16; msk <<= 1) mx = fmaxf(mx, __shfl_xor(mx, msk));
            float sm = 0.f;
#pragma unroll
            for (int t = 0; t < 8; ++t) sm += __expf(acc[t][r] - mx);
#pragma unroll
            for (int msk = 1; msk < 16; msk <<= 1) sm += __shfl_xor(sm, msk);
            float l = mx + __logf(sm);
            int rown = gbase + quad * 4 + r;
            if (rown < N_NODES) {
                float* op = out + (size_t)rown * 128 + m;
#pragma unroll
                for (int t = 0; t < 8; ++t) op[16 * t] = acc[t][r] - l;
            }
        }
#pragma unroll
        for (int ks = 0; ks < 4; ++ks) a[ks] = an[ks];
    }
}

// ---------------- launch ----------------

extern "C" void kernel_launch(void* const* d_in, const int* in_sizes, int n_in,
                              void* d_out, int out_size, void* d_ws, size_t ws_size,
                              hipStream_t stream) {
    const float* x = (const float*)d_in[0];
    const float* W = (const float*)d_in[1];
    const float* b = (const float*)d_in[2];
    const int* edge = (const int*)d_in[3];
    const int* row = edge;             // source nodes j
    const int* col = edge + N_EDGES;   // target nodes i
    float* out = (float*)d_out;

    // workspace layout (4B word offsets)
    int*      bcnt  = (int*)d_ws;                     // NBUCK padded ctrs (50KB) - only memset
    float*    dinv  = (float*)(bcnt + NBUCK * CPAD + 256);
    float*    dinv2 = dinv + 102400;                  // 100k
    int2*     rp2   = (int2*)(dinv2 + 102400);        // 100k (start,end)
    unsigned* csr   = (unsigned*)(rp2 + 102400);      // NBUCK*BSPAN = 1.6M (6.4 MB)
    uint2*    xb    = (uint2*)(csr + (size_t)NBUCK * BSPAN);  // (N+1)*32 uint2 = 25.6 MB
    uint2*    h1b   = xb + 32 * (N_NODES + 1);        // (N+1)*32 uint2
    uint2*    h2b   = xb;                             // reuse: xb dead after hop 1
    // stage aliases h1b past its zero-row (h1b is only written by k_hop #1,
    // which launches after k_build has consumed stage; stream order serializes).
    unsigned* stage = (unsigned*)(h1b + 32);          // NBUCK*SCAP*4 = 4.8 MB
    uint2*    wbf   = h1b + 32 * (N_NODES + 1);       // 4096 uint2 = 32 KB bf16 W

    int nb_prep = (N_NODES * 32 + 255) / 256;         // 12500

    (void)hipMemsetAsync(bcnt, 0, (size_t)NBUCK * CPAD * 4, stream);   // 50 KB
    k_fill3<<<FILL_BLOCKS, 256, 0, stream>>>(row, col, bcnt, stage);
    k_build<<<NBUCK, 256, 0, stream>>>(bcnt, stage, csr, rp2, dinv, dinv2);
    k_prep<<<nb_prep, 256, 0, stream>>>((const float4*)x, dinv, (const float4*)W, wbf, xb, h1b);

    int hop_blocks = (N_NODES / 2 * 64) / 256;        // 12500: one wave per 2 nodes
    k_hop<<<hop_blocks, 256, 0, stream>>>(rp2, csr, dinv2, xb, h1b);   // -> y1
    k_hop<<<hop_blocks, 256, 0, stream>>>(rp2, csr, dinv, h1b, h2b);   // -> h2

    k_gemm_lsm_mfma<<<512, 256, 0, stream>>>((const unsigned short*)(h2b + 32),
                                             (const unsigned short*)wbf, b, out);
}